// Round 15
// baseline (362.712 us; speedup 1.0000x reference)
//
#include <hip/hip_runtime.h>

#define NN 50000
#define NF 256
#define NH 256
#define NC 40
#define NE 800000
#define CAP 64   // bucket capacity; P(deg>64)~1e-20 for Binomial(800k,1/50k)

typedef _Float16 f16x8 __attribute__((ext_vector_type(8)));
typedef float f32x4 __attribute__((ext_vector_type(4)));

__device__ __forceinline__ float f16f(unsigned short u) {
  union { unsigned short u; _Float16 h; } a; a.u = u;
  return (float)a.h;
}
__device__ __forceinline__ unsigned short f16u(float f) {
  union { unsigned short u; _Float16 h; } a; a.h = (_Float16)f;
  return a.u;
}

__device__ __forceinline__ void gl16(const void* g, void* l) {
  __builtin_amdgcn_global_load_lds(
      (const __attribute__((address_space(1))) unsigned int*)g,
      (__attribute__((address_space(3))) unsigned int*)l, 16, 0, 0);
}

// ---------------- bucketing ----------------

__global__ void bucket_kernel(const int* __restrict__ src, const int* __restrict__ dst,
                              int* __restrict__ cnt, unsigned short* __restrict__ bucket) {
  int e = blockIdx.x * blockDim.x + threadIdx.x;
  if (e < NE) {
    int d = dst[e], s = src[e];
    int c = atomicAdd(&cnt[d], 1);
    if (c < CAP) bucket[(size_t)d * CAP + c] = (unsigned short)s;
  }
}

// ---------------- prep: weight conversion (W4 64 rows) + dis ----------------

__global__ void prep_kernel(const int* __restrict__ cnt, float* __restrict__ dis,
                            const float* __restrict__ W1, const float* __restrict__ W2,
                            const float* __restrict__ W3, const float* __restrict__ W4,
                            unsigned short* __restrict__ Wt1, unsigned short* __restrict__ Wt2,
                            unsigned short* __restrict__ Wt3, unsigned short* __restrict__ Wt4) {
  int idx = blockIdx.x * blockDim.x + threadIdx.x;
  if (idx < 212992) {
    const float* W; unsigned short* Wt; int N;
    if (idx < 65536)       { W = W1; Wt = Wt1; N = 256; }
    else if (idx < 131072) { W = W2; Wt = Wt2; N = 256; idx -= 65536; }
    else if (idx < 196608) { W = W3; Wt = Wt3; N = 256; idx -= 131072; }
    else                   { W = W4; Wt = Wt4; N = 40;  idx -= 196608; }
    int n = idx >> 8, k = idx & 255;
    float v = (n < N) ? W[k * N + n] : 0.0f;
    Wt[idx] = f16u(v);
  } else {
    int i = idx - 212992;
    if (i < NN) dis[i] = rsqrtf((float)(cnt[i] + 1));
  }
}

// ---------------- layer-1 GEMM: C[M][256] = x[M][256](f32) * Wt1[256][256]^T ----------------

__global__ __launch_bounds__(256, 4) void gemm_l1(
    const float* __restrict__ Ain, const unsigned short* __restrict__ Bt,
    unsigned short* __restrict__ Cout, int M) {
  __shared__ unsigned short ldsA[64 * 64];    // 8 KB
  __shared__ unsigned short ldsB[256 * 64];   // 32 KB

  int tid = threadIdx.x;
  int rowBase = blockIdx.x * 64;
  int w = tid >> 6, lane = tid & 63;
  int l15 = lane & 15, l4 = lane >> 4;

  f32x4 acc[4][4] = {};

  for (int kt = 0; kt < 4; ++kt) {
#pragma unroll
    for (int c = 0; c < 2; ++c) {
      int gi = c * 256 + tid;
      int row = gi >> 3, gp = gi & 7;
      int gsrc = gp ^ (row & 7);
      int koff = kt * 64 + gsrc * 8;
      int ar = rowBase + row; ar = ar < M ? ar : M - 1;
      const float* Af = Ain + (size_t)ar * 256 + koff;
      float4 v0 = *(const float4*)Af;
      float4 v1 = *(const float4*)(Af + 4);
      f16x8 h = {(_Float16)v0.x, (_Float16)v0.y, (_Float16)v0.z, (_Float16)v0.w,
                 (_Float16)v1.x, (_Float16)v1.y, (_Float16)v1.z, (_Float16)v1.w};
      *(f16x8*)&ldsA[gi * 8] = h;
    }
#pragma unroll
    for (int c = 0; c < 8; ++c) {
      int gi = c * 256 + tid;
      int row = gi >> 3, gp = gi & 7;
      int gsrc = gp ^ (row & 7);
      int koff = kt * 64 + gsrc * 8;
      gl16(Bt + (size_t)row * 256 + koff, &ldsB[gi * 8]);
    }
    __syncthreads();

#pragma unroll
    for (int ks = 0; ks < 2; ++ks) {
      f16x8 a[4], b[4];
      int g = ks * 4 + l4;
#pragma unroll
      for (int mi = 0; mi < 4; ++mi) {
        int arow = mi * 16 + l15;
        int gp = g ^ (arow & 7);
        a[mi] = *(const f16x8*)&ldsA[arow * 64 + gp * 8];
      }
#pragma unroll
      for (int ni = 0; ni < 4; ++ni) {
        int brow = w * 64 + ni * 16 + l15;
        int gp = g ^ (brow & 7);
        b[ni] = *(const f16x8*)&ldsB[brow * 64 + gp * 8];
      }
#pragma unroll
      for (int mi = 0; mi < 4; ++mi)
#pragma unroll
        for (int ni = 0; ni < 4; ++ni)
          acc[mi][ni] = __builtin_amdgcn_mfma_f32_16x16x32_f16(a[mi], b[ni], acc[mi][ni], 0, 0, 0);
    }
    __syncthreads();
  }

#pragma unroll
  for (int ni = 0; ni < 4; ++ni) {
    int col = w * 64 + ni * 16 + l15;
#pragma unroll
    for (int mi = 0; mi < 4; ++mi) {
      f32x4 v = acc[mi][ni];
#pragma unroll
      for (int i = 0; i < 4; ++i) {
        int r = rowBase + mi * 16 + l4 * 4 + i;
        if (r < M) Cout[(size_t)r * 256 + col] = f16u(v[i]);
      }
    }
  }
}

// ---------------- fused agg(layer k) + gemm(layer k+1) ----------------
// 512 threads = 8 waves; block owns 64 nodes. Phase A: wave aggregates 8 nodes,
// writes relu'd fp16 rows into swizzled ldsA[64][256]. Phase B: BM=64 x NOUT GEMM,
// A from ldsA, B staged via gl16. Tprev stride 256; Tnext stride NOUT.

template <int NOUT>
__global__ __launch_bounds__(512, 2) void fused_ag(
    const unsigned short* __restrict__ Tprev, unsigned short* __restrict__ Tnext,
    const int* __restrict__ cnt, const unsigned short* __restrict__ bucket,
    const float* __restrict__ dis, const float* __restrict__ b,
    const unsigned short* __restrict__ Wt) {
  __shared__ unsigned short ldsA[64 * 256];   // 32 KB, granule-swizzled rows
  __shared__ unsigned short ldsB[NOUT * 64];  // 32 KB (256) / 8 KB (64)

  int tid = threadIdx.x;
  int wave = tid >> 6, lane = tid & 63;
  int nodeBase = blockIdx.x * 64;
  const ushort4* Tv = (const ushort4*)Tprev;
  float4 bv = ((const float4*)b)[lane];

  // ---- Phase A: aggregate 8 nodes per wave ----
  for (int i = 0; i < 8; ++i) {
    int r = wave * 8 + i;
    int node = nodeBase + r;
    if (node < NN) {
      float d = dis[node];
      int cv = cnt[node];
      int deg = cv < CAP ? cv : CAP;
      float w0 = d * d;
      ushort4 t = Tv[(size_t)node * 64 + lane];
      float ax = bv.x + w0 * f16f(t.x), ay = bv.y + w0 * f16f(t.y);
      float az = bv.z + w0 * f16f(t.z), aw = bv.w + w0 * f16f(t.w);
      const unsigned short* bk = bucket + (size_t)node * CAP;
      int j = 0;
      for (; j + 4 <= deg; j += 4) {
        int s0 = bk[j], s1 = bk[j + 1], s2 = bk[j + 2], s3 = bk[j + 3];
        ushort4 t0 = Tv[(size_t)s0 * 64 + lane];
        ushort4 t1 = Tv[(size_t)s1 * 64 + lane];
        ushort4 t2 = Tv[(size_t)s2 * 64 + lane];
        ushort4 t3 = Tv[(size_t)s3 * 64 + lane];
        float f0 = d * dis[s0], f1 = d * dis[s1];
        float f2 = d * dis[s2], f3 = d * dis[s3];
        ax += f0 * f16f(t0.x) + f1 * f16f(t1.x) + f2 * f16f(t2.x) + f3 * f16f(t3.x);
        ay += f0 * f16f(t0.y) + f1 * f16f(t1.y) + f2 * f16f(t2.y) + f3 * f16f(t3.y);
        az += f0 * f16f(t0.z) + f1 * f16f(t1.z) + f2 * f16f(t2.z) + f3 * f16f(t3.z);
        aw += f0 * f16f(t0.w) + f1 * f16f(t1.w) + f2 * f16f(t2.w) + f3 * f16f(t3.w);
      }
      for (; j < deg; ++j) {
        int s = bk[j];
        float f = d * dis[s];
        ushort4 ts = Tv[(size_t)s * 64 + lane];
        ax += f * f16f(ts.x); ay += f * f16f(ts.y);
        az += f * f16f(ts.z); aw += f * f16f(ts.w);
      }
      ax = fmaxf(ax, 0.f); ay = fmaxf(ay, 0.f);
      az = fmaxf(az, 0.f); aw = fmaxf(aw, 0.f);
      ushort4 h;
      h.x = f16u(ax); h.y = f16u(ay); h.z = f16u(az); h.w = f16u(aw);
      int gp = (lane >> 1) ^ (r & 7);                       // swizzled 16B granule
      *(ushort4*)&ldsA[r * 256 + gp * 8 + (lane & 1) * 4] = h;
    }
  }
  __syncthreads();

  // ---- Phase B: GEMM 64 x NOUT = ldsA(64x256) x Wt(NOUT x 256)^T ----
  constexpr int NI = NOUT / 64;          // b-fragments per wave (4 or 1)
  int wr = wave >> 2, wc = wave & 3;     // 2x4 wave grid: 32 rows x NOUT/4 cols
  int l15 = lane & 15, l4 = lane >> 4;
  f32x4 acc[2][NI] = {};

  for (int kt = 0; kt < 4; ++kt) {
    constexpr int NG = NOUT * 8;         // 16B granules in B tile
#pragma unroll
    for (int c = 0; c < NG / 512; ++c) {
      int gi = c * 512 + tid;
      int row = gi >> 3, gp = gi & 7;
      int gsrc = gp ^ (row & 7);
      gl16(Wt + (size_t)row * 256 + kt * 64 + gsrc * 8, &ldsB[gi * 8]);
    }
    __syncthreads();

#pragma unroll
    for (int ks = 0; ks < 2; ++ks) {
      f16x8 a[2], bf[NI];
#pragma unroll
      for (int mi = 0; mi < 2; ++mi) {
        int arow = wr * 32 + mi * 16 + l15;
        int ga = kt * 8 + ks * 4 + l4;
        int gp = ga ^ (arow & 7);
        a[mi] = *(const f16x8*)&ldsA[arow * 256 + gp * 8];
      }
#pragma unroll
      for (int ni = 0; ni < NI; ++ni) {
        int brow = wc * (NOUT / 4) + ni * 16 + l15;
        int g = ks * 4 + l4;
        int gp = g ^ (brow & 7);
        bf[ni] = *(const f16x8*)&ldsB[brow * 64 + gp * 8];
      }
#pragma unroll
      for (int mi = 0; mi < 2; ++mi)
#pragma unroll
        for (int ni = 0; ni < NI; ++ni)
          acc[mi][ni] = __builtin_amdgcn_mfma_f32_16x16x32_f16(a[mi], bf[ni], acc[mi][ni], 0, 0, 0);
    }
    __syncthreads();
  }

#pragma unroll
  for (int ni = 0; ni < NI; ++ni) {
    int col = wc * (NOUT / 4) + ni * 16 + l15;
#pragma unroll
    for (int mi = 0; mi < 2; ++mi) {
      f32x4 v = acc[mi][ni];
#pragma unroll
      for (int i = 0; i < 4; ++i) {
        int r = nodeBase + wr * 32 + mi * 16 + l4 * 4 + i;
        if (r < NN) Tnext[(size_t)r * NOUT + col] = f16u(v[i]);
      }
    }
  }
}

// ---------------- final aggregation (layer 4): T stride 64, f32 out ----------------

__global__ __launch_bounds__(256) void agg40_kernel(
    const unsigned short* __restrict__ T, float* __restrict__ O,
    const int* __restrict__ cnt, const unsigned short* __restrict__ bucket,
    const float* __restrict__ dis, const float* __restrict__ b) {
  int node = (blockIdx.x * blockDim.x + threadIdx.x) >> 6;
  int lane = threadIdx.x & 63;
  if (node >= NN) return;
  float d = dis[node];
  int cv = cnt[node];
  int deg = cv < CAP ? cv : CAP;
  const unsigned short* bk = bucket + (size_t)node * CAP;
  if (lane < NC) {
    float acc = b[lane] + d * d * f16f(T[(size_t)node * 64 + lane]);
    int j = 0;
    for (; j + 4 <= deg; j += 4) {
      int s0 = bk[j], s1 = bk[j + 1], s2 = bk[j + 2], s3 = bk[j + 3];
      float t0 = f16f(T[(size_t)s0 * 64 + lane]);
      float t1 = f16f(T[(size_t)s1 * 64 + lane]);
      float t2 = f16f(T[(size_t)s2 * 64 + lane]);
      float t3 = f16f(T[(size_t)s3 * 64 + lane]);
      acc += d * dis[s0] * t0 + d * dis[s1] * t1 + d * dis[s2] * t2 + d * dis[s3] * t3;
    }
    for (; j < deg; ++j) {
      int s = bk[j];
      acc += d * dis[s] * f16f(T[(size_t)s * 64 + lane]);
    }
    O[(size_t)node * NC + lane] = acc;
  }
}

// ---------------- launch ----------------

extern "C" void kernel_launch(void* const* d_in, const int* in_sizes, int n_in,
                              void* d_out, int out_size, void* d_ws, size_t ws_size,
                              hipStream_t stream) {
  const float* x  = (const float*)d_in[0];
  const int* edge = (const int*)d_in[1];
  const float* W1 = (const float*)d_in[2];
  const float* b1 = (const float*)d_in[3];
  const float* W2 = (const float*)d_in[4];
  const float* b2 = (const float*)d_in[5];
  const float* W3 = (const float*)d_in[6];
  const float* b3 = (const float*)d_in[7];
  const float* W4 = (const float*)d_in[8];
  const float* b4 = (const float*)d_in[9];
  float* out = (float*)d_out;

  char* p = (char*)d_ws;
  unsigned short* Ta = (unsigned short*)p; p += (size_t)NN * NH * 2;  // 25.6 MB
  unsigned short* Tb = (unsigned short*)p; p += (size_t)NN * NH * 2;  // 25.6 MB
  int* cnt = (int*)p;                p += (size_t)NN * 4;
  float* dis = (float*)p;            p += (size_t)NN * 4;
  unsigned short* bucket = (unsigned short*)p; p += (size_t)NN * CAP * 2;  // 6.4 MB
  unsigned short* Wt1 = (unsigned short*)p; p += 256 * 256 * 2;
  unsigned short* Wt2 = (unsigned short*)p; p += 256 * 256 * 2;
  unsigned short* Wt3 = (unsigned short*)p; p += 256 * 256 * 2;
  unsigned short* Wt4 = (unsigned short*)p; p += 64 * 256 * 2;

  const int* e_src = edge;
  const int* e_dst = edge + NE;

  hipMemsetAsync(cnt, 0, (size_t)NN * 4, stream);

  bucket_kernel<<<(NE + 255) / 256, 256, 0, stream>>>(e_src, e_dst, cnt, bucket);
  prep_kernel<<<(212992 + NN + 255) / 256, 256, 0, stream>>>(cnt, dis, W1, W2, W3, W4,
                                                             Wt1, Wt2, Wt3, Wt4);

  int gemmBlocks = (NN + 63) / 64;  // 782
  int aggBlocks = (NN * 64 + 255) / 256;

  gemm_l1<<<gemmBlocks, 256, 0, stream>>>(x, Wt1, Ta, NN);
  fused_ag<256><<<gemmBlocks, 512, 0, stream>>>(Ta, Tb, cnt, bucket, dis, b1, Wt2);
  fused_ag<256><<<gemmBlocks, 512, 0, stream>>>(Tb, Ta, cnt, bucket, dis, b2, Wt3);
  fused_ag<64><<<gemmBlocks, 512, 0, stream>>>(Ta, Tb, cnt, bucket, dis, b3, Wt4);
  agg40_kernel<<<aggBlocks, 256, 0, stream>>>(Tb, out, cnt, bucket, dis, b4);
}

// Round 16
// 329.352 us; speedup vs baseline: 1.1013x; 1.1013x over previous
//
#include <hip/hip_runtime.h>

#define NN 50000
#define NF 256
#define NH 256
#define NC 40
#define NE 800000
#define CAP 64   // bucket capacity; P(deg>64)~1e-20 for Binomial(800k,1/50k)

typedef _Float16 f16x8 __attribute__((ext_vector_type(8)));
typedef float f32x4 __attribute__((ext_vector_type(4)));

__device__ __forceinline__ float f16f(unsigned short u) {
  union { unsigned short u; _Float16 h; } a; a.u = u;
  return (float)a.h;
}
__device__ __forceinline__ unsigned short f16u(float f) {
  union { unsigned short u; _Float16 h; } a; a.h = (_Float16)f;
  return a.u;
}

__device__ __forceinline__ void gl16(const void* g, void* l) {
  __builtin_amdgcn_global_load_lds(
      (const __attribute__((address_space(1))) unsigned int*)g,
      (__attribute__((address_space(3))) unsigned int*)l, 16, 0, 0);
}

// ---------------- bucketing: standalone, zero LDS, max occupancy ----------------
// (Fusing this or agg into bigger kernels falsified twice: occupancy tax > fusion win.)

__global__ void bucket_kernel(const int* __restrict__ src, const int* __restrict__ dst,
                              int* __restrict__ cnt, unsigned short* __restrict__ bucket) {
  int e = blockIdx.x * blockDim.x + threadIdx.x;
  if (e < NE) {
    int d = dst[e], s = src[e];
    int c = atomicAdd(&cnt[d], 1);
    if (c < CAP) bucket[(size_t)d * CAP + c] = (unsigned short)s;
  }
}

// ---------------- prep: weight conversion (W4 only 64 rows) + dis from cnt ----------------

__global__ void prep_kernel(const int* __restrict__ cnt, float* __restrict__ dis,
                            const float* __restrict__ W1, const float* __restrict__ W2,
                            const float* __restrict__ W3, const float* __restrict__ W4,
                            unsigned short* __restrict__ Wt1, unsigned short* __restrict__ Wt2,
                            unsigned short* __restrict__ Wt3, unsigned short* __restrict__ Wt4) {
  int idx = blockIdx.x * blockDim.x + threadIdx.x;
  if (idx < 212992) {
    const float* W; unsigned short* Wt; int N;
    if (idx < 65536)       { W = W1; Wt = Wt1; N = 256; }
    else if (idx < 131072) { W = W2; Wt = Wt2; N = 256; idx -= 65536; }
    else if (idx < 196608) { W = W3; Wt = Wt3; N = 256; idx -= 131072; }
    else                   { W = W4; Wt = Wt4; N = 40;  idx -= 196608; }  // 64 rows
    int n = idx >> 8, k = idx & 255;
    float v = (n < N) ? W[k * N + n] : 0.0f;
    Wt[idx] = f16u(v);
  } else {
    int i = idx - 212992;
    if (i < NN) dis[i] = rsqrtf((float)(cnt[i] + 1));
  }
}

// ---------------- fp16 MFMA GEMM: C[M][256] = A[M][256] * Bt[256][256]^T ----------------
// BM=64, BN=256 (A staged once). 4 waves, each owns 64 rows x 64 cols. LDS 40 KB.

template <bool AF32>
__global__ __launch_bounds__(256, 4) void gemm_f16(
    const void* __restrict__ Ain, const unsigned short* __restrict__ Bt,
    unsigned short* __restrict__ Cout, int M) {
  __shared__ unsigned short ldsA[64 * 64];    // 8 KB
  __shared__ unsigned short ldsB[256 * 64];   // 32 KB

  int tid = threadIdx.x;
  int rowBase = blockIdx.x * 64;
  int w = tid >> 6, lane = tid & 63;
  int l15 = lane & 15, l4 = lane >> 4;

  f32x4 acc[4][4] = {};

  for (int kt = 0; kt < 4; ++kt) {
#pragma unroll
    for (int c = 0; c < 2; ++c) {
      int gi = c * 256 + tid;
      int row = gi >> 3, gp = gi & 7;
      int gsrc = gp ^ (row & 7);
      int koff = kt * 64 + gsrc * 8;
      int ar = rowBase + row; ar = ar < M ? ar : M - 1;
      if (AF32) {
        const float* Af = (const float*)Ain + (size_t)ar * 256 + koff;
        float4 v0 = *(const float4*)Af;
        float4 v1 = *(const float4*)(Af + 4);
        f16x8 h = {(_Float16)v0.x, (_Float16)v0.y, (_Float16)v0.z, (_Float16)v0.w,
                   (_Float16)v1.x, (_Float16)v1.y, (_Float16)v1.z, (_Float16)v1.w};
        *(f16x8*)&ldsA[gi * 8] = h;
      } else {
        gl16((const unsigned short*)Ain + (size_t)ar * 256 + koff, &ldsA[gi * 8]);
      }
    }
#pragma unroll
    for (int c = 0; c < 8; ++c) {
      int gi = c * 256 + tid;
      int row = gi >> 3, gp = gi & 7;
      int gsrc = gp ^ (row & 7);
      int koff = kt * 64 + gsrc * 8;
      gl16(Bt + (size_t)row * 256 + koff, &ldsB[gi * 8]);
    }
    __syncthreads();

#pragma unroll
    for (int ks = 0; ks < 2; ++ks) {
      f16x8 a[4], b[4];
      int g = ks * 4 + l4;
#pragma unroll
      for (int mi = 0; mi < 4; ++mi) {
        int arow = mi * 16 + l15;
        int gp = g ^ (arow & 7);
        a[mi] = *(const f16x8*)&ldsA[arow * 64 + gp * 8];
      }
#pragma unroll
      for (int ni = 0; ni < 4; ++ni) {
        int brow = w * 64 + ni * 16 + l15;
        int gp = g ^ (brow & 7);
        b[ni] = *(const f16x8*)&ldsB[brow * 64 + gp * 8];
      }
#pragma unroll
      for (int mi = 0; mi < 4; ++mi)
#pragma unroll
        for (int ni = 0; ni < 4; ++ni)
          acc[mi][ni] = __builtin_amdgcn_mfma_f32_16x16x32_f16(a[mi], b[ni], acc[mi][ni], 0, 0, 0);
    }
    __syncthreads();
  }

#pragma unroll
  for (int ni = 0; ni < 4; ++ni) {
    int col = w * 64 + ni * 16 + l15;
#pragma unroll
    for (int mi = 0; mi < 4; ++mi) {
      f32x4 v = acc[mi][ni];
#pragma unroll
      for (int i = 0; i < 4; ++i) {
        int r = rowBase + mi * 16 + l4 * 4 + i;
        if (r < M) Cout[(size_t)r * 256 + col] = f16u(v[i]);
      }
    }
  }
}

// ---------------- layer-4 GEMM: C[M][64] = A[M][256] * Bt[64][256]^T ----------------
// BM=64, BN=64. 4 waves, wave w owns 64 rows x 16 cols. LDS 16 KB.

__global__ __launch_bounds__(256) void gemm_n64(
    const unsigned short* __restrict__ A, const unsigned short* __restrict__ Bt,
    unsigned short* __restrict__ Cout, int M) {
  __shared__ unsigned short ldsA[64 * 64];   // 8 KB
  __shared__ unsigned short ldsB[64 * 64];   // 8 KB

  int tid = threadIdx.x;
  int rowBase = blockIdx.x * 64;
  int w = tid >> 6, lane = tid & 63;
  int l15 = lane & 15, l4 = lane >> 4;

  f32x4 acc[4] = {};

  for (int kt = 0; kt < 4; ++kt) {
#pragma unroll
    for (int c = 0; c < 2; ++c) {
      int gi = c * 256 + tid;
      int row = gi >> 3, gp = gi & 7;
      int gsrc = gp ^ (row & 7);
      int koff = kt * 64 + gsrc * 8;
      int ar = rowBase + row; ar = ar < M ? ar : M - 1;
      gl16(A + (size_t)ar * 256 + koff, &ldsA[gi * 8]);
      gl16(Bt + (size_t)row * 256 + koff, &ldsB[gi * 8]);
    }
    __syncthreads();

#pragma unroll
    for (int ks = 0; ks < 2; ++ks) {
      f16x8 a[4], b;
      int g = ks * 4 + l4;
#pragma unroll
      for (int mi = 0; mi < 4; ++mi) {
        int arow = mi * 16 + l15;
        int gp = g ^ (arow & 7);
        a[mi] = *(const f16x8*)&ldsA[arow * 64 + gp * 8];
      }
      {
        int brow = w * 16 + l15;
        int gp = g ^ (brow & 7);
        b = *(const f16x8*)&ldsB[brow * 64 + gp * 8];
      }
#pragma unroll
      for (int mi = 0; mi < 4; ++mi)
        acc[mi] = __builtin_amdgcn_mfma_f32_16x16x32_f16(a[mi], b, acc[mi], 0, 0, 0);
    }
    __syncthreads();
  }

  int col = w * 16 + l15;
#pragma unroll
  for (int mi = 0; mi < 4; ++mi) {
    f32x4 v = acc[mi];
#pragma unroll
    for (int i = 0; i < 4; ++i) {
      int r = rowBase + mi * 16 + l4 * 4 + i;
      if (r < M) Cout[(size_t)r * 64 + col] = f16u(v[i]);
    }
  }
}

// ---------------- aggregation: one wave per node, fp16 T, ushort bucket ----------------

__global__ __launch_bounds__(256) void agg256_kernel(
    const unsigned short* __restrict__ T, unsigned short* __restrict__ P,
    const int* __restrict__ cnt, const unsigned short* __restrict__ bucket,
    const float* __restrict__ dis, const float* __restrict__ b) {
  int node = (blockIdx.x * blockDim.x + threadIdx.x) >> 6;
  int lane = threadIdx.x & 63;
  if (node >= NN) return;
  const ushort4* Tv = (const ushort4*)T;
  float4 bv = ((const float4*)b)[lane];
  float d = dis[node];
  int cv = cnt[node];
  int deg = cv < CAP ? cv : CAP;
  float w0 = d * d;
  ushort4 t = Tv[(size_t)node * 64 + lane];
  float ax = bv.x + w0 * f16f(t.x), ay = bv.y + w0 * f16f(t.y);
  float az = bv.z + w0 * f16f(t.z), aw = bv.w + w0 * f16f(t.w);
  const unsigned short* bk = bucket + (size_t)node * CAP;
  int j = 0;
  for (; j + 4 <= deg; j += 4) {
    int s0 = bk[j], s1 = bk[j + 1], s2 = bk[j + 2], s3 = bk[j + 3];
    ushort4 t0 = Tv[(size_t)s0 * 64 + lane];
    ushort4 t1 = Tv[(size_t)s1 * 64 + lane];
    ushort4 t2 = Tv[(size_t)s2 * 64 + lane];
    ushort4 t3 = Tv[(size_t)s3 * 64 + lane];
    float f0 = d * dis[s0], f1 = d * dis[s1];
    float f2 = d * dis[s2], f3 = d * dis[s3];
    ax += f0 * f16f(t0.x) + f1 * f16f(t1.x) + f2 * f16f(t2.x) + f3 * f16f(t3.x);
    ay += f0 * f16f(t0.y) + f1 * f16f(t1.y) + f2 * f16f(t2.y) + f3 * f16f(t3.y);
    az += f0 * f16f(t0.z) + f1 * f16f(t1.z) + f2 * f16f(t2.z) + f3 * f16f(t3.z);
    aw += f0 * f16f(t0.w) + f1 * f16f(t1.w) + f2 * f16f(t2.w) + f3 * f16f(t3.w);
  }
  for (; j < deg; ++j) {
    int s = bk[j];
    float f = d * dis[s];
    ushort4 ts = Tv[(size_t)s * 64 + lane];
    ax += f * f16f(ts.x); ay += f * f16f(ts.y);
    az += f * f16f(ts.z); aw += f * f16f(ts.w);
  }
  ax = fmaxf(ax, 0.f); ay = fmaxf(ay, 0.f);
  az = fmaxf(az, 0.f); aw = fmaxf(aw, 0.f);
  ushort4 h;
  h.x = f16u(ax); h.y = f16u(ay); h.z = f16u(az); h.w = f16u(aw);
  ((ushort4*)P)[(size_t)node * 64 + lane] = h;
}

// layer-4 aggregation: T stride 64
__global__ __launch_bounds__(256) void agg40_kernel(
    const unsigned short* __restrict__ T, float* __restrict__ O,
    const int* __restrict__ cnt, const unsigned short* __restrict__ bucket,
    const float* __restrict__ dis, const float* __restrict__ b) {
  int node = (blockIdx.x * blockDim.x + threadIdx.x) >> 6;
  int lane = threadIdx.x & 63;
  if (node >= NN) return;
  float d = dis[node];
  int cv = cnt[node];
  int deg = cv < CAP ? cv : CAP;
  const unsigned short* bk = bucket + (size_t)node * CAP;
  if (lane < NC) {
    float acc = b[lane] + d * d * f16f(T[(size_t)node * 64 + lane]);
    int j = 0;
    for (; j + 4 <= deg; j += 4) {
      int s0 = bk[j], s1 = bk[j + 1], s2 = bk[j + 2], s3 = bk[j + 3];
      float t0 = f16f(T[(size_t)s0 * 64 + lane]);
      float t1 = f16f(T[(size_t)s1 * 64 + lane]);
      float t2 = f16f(T[(size_t)s2 * 64 + lane]);
      float t3 = f16f(T[(size_t)s3 * 64 + lane]);
      acc += d * dis[s0] * t0 + d * dis[s1] * t1 + d * dis[s2] * t2 + d * dis[s3] * t3;
    }
    for (; j < deg; ++j) {
      int s = bk[j];
      acc += d * dis[s] * f16f(T[(size_t)s * 64 + lane]);
    }
    O[(size_t)node * NC + lane] = acc;
  }
}

// ---------------- launch ----------------

extern "C" void kernel_launch(void* const* d_in, const int* in_sizes, int n_in,
                              void* d_out, int out_size, void* d_ws, size_t ws_size,
                              hipStream_t stream) {
  const float* x  = (const float*)d_in[0];
  const int* edge = (const int*)d_in[1];
  const float* W1 = (const float*)d_in[2];
  const float* b1 = (const float*)d_in[3];
  const float* W2 = (const float*)d_in[4];
  const float* b2 = (const float*)d_in[5];
  const float* W3 = (const float*)d_in[6];
  const float* b3 = (const float*)d_in[7];
  const float* W4 = (const float*)d_in[8];
  const float* b4 = (const float*)d_in[9];
  float* out = (float*)d_out;

  char* p = (char*)d_ws;
  unsigned short* T16 = (unsigned short*)p; p += (size_t)NN * NH * 2;  // 25.6 MB
  unsigned short* P16 = (unsigned short*)p; p += (size_t)NN * NH * 2;  // 25.6 MB
  int* cnt = (int*)p;                p += (size_t)NN * 4;
  float* dis = (float*)p;            p += (size_t)NN * 4;
  unsigned short* bucket = (unsigned short*)p; p += (size_t)NN * CAP * 2;  // 6.4 MB
  unsigned short* Wt1 = (unsigned short*)p; p += 256 * 256 * 2;
  unsigned short* Wt2 = (unsigned short*)p; p += 256 * 256 * 2;
  unsigned short* Wt3 = (unsigned short*)p; p += 256 * 256 * 2;
  unsigned short* Wt4 = (unsigned short*)p; p += 64 * 256 * 2;   // 64 padded rows

  const int* e_src = edge;
  const int* e_dst = edge + NE;

  hipMemsetAsync(cnt, 0, (size_t)NN * 4, stream);

  bucket_kernel<<<(NE + 255) / 256, 256, 0, stream>>>(e_src, e_dst, cnt, bucket);
  prep_kernel<<<(212992 + NN + 255) / 256, 256, 0, stream>>>(cnt, dis, W1, W2, W3, W4,
                                                             Wt1, Wt2, Wt3, Wt4);

  int gemmBlocks = (NN + 63) / 64;  // 782
  int aggBlocks = (NN * 64 + 255) / 256;

  gemm_f16<true><<<gemmBlocks, 256, 0, stream>>>(x, Wt1, T16, NN);
  agg256_kernel<<<aggBlocks, 256, 0, stream>>>(T16, P16, cnt, bucket, dis, b1);
  gemm_f16<false><<<gemmBlocks, 256, 0, stream>>>(P16, Wt2, T16, NN);
  agg256_kernel<<<aggBlocks, 256, 0, stream>>>(T16, P16, cnt, bucket, dis, b2);
  gemm_f16<false><<<gemmBlocks, 256, 0, stream>>>(P16, Wt3, T16, NN);
  agg256_kernel<<<aggBlocks, 256, 0, stream>>>(T16, P16, cnt, bucket, dis, b3);
  gemm_n64<<<gemmBlocks, 256, 0, stream>>>(P16, Wt4, T16, NN);
  agg40_kernel<<<aggBlocks, 256, 0, stream>>>(T16, out, cnt, bucket, dis, b4);
}